// Round 3
// baseline (1500.776 us; speedup 1.0000x reference)
//
#include <hip/hip_runtime.h>
#include <math.h>

#define BKS 60      // B*K sequences
#define TL  1000    // T
#define NF  128     // N features
#define NP  132     // padded LDS row stride (float4-aligned, breaks bank patterns)
#define SD  12      // state dim S
#define RD  8       // dt rank
#define NCH 25      // scan chunks
#define CLEN 40     // chunk length (NCH*CLEN == TL)
#define NTOK (BKS*TL)

__device__ __forceinline__ float siluf(float x){ return x / (1.f + __expf(-x)); }
__device__ __forceinline__ float softplusf(float x){
  if (x > 20.f) return x;
  float e = __expf(x);
  return (x < -20.f) ? e : __logf(1.f + e);
}

// ---- K0: x (B,N,T,K) -> seq (B*K, T, N), one block per (b,t)
__global__ __launch_bounds__(256) void k_ingest(const float* __restrict__ x, float* __restrict__ seq){
  const int b = blockIdx.x / TL, t = blockIdx.x % TL;
  __shared__ float tile[30*NF];
  for (int e = threadIdx.x; e < 30*NF; e += 256){
    int n = e / 30, k = e - n*30;
    tile[k*NF + n] = x[((size_t)(b*NF + n)*TL + t)*30 + k];
  }
  __syncthreads();
  const size_t base = ((size_t)b*30)*TL*NF + (size_t)t*NF;
  for (int e = threadIdx.x; e < 30*NF; e += 256){
    int k = e >> 7, n = e & 127;
    seq[base + (size_t)k*TL*NF + n] = tile[e];
  }
}

// ---- K1: LayerNorm + in_proj (2N x N), 16 tokens/block, 2 output cols per thread
__global__ __launch_bounds__(256) void k_ln_inproj(
    const float* __restrict__ seq, const float* __restrict__ lnw, const float* __restrict__ lnb,
    const float* __restrict__ iw, const float* __restrict__ ib,
    float* __restrict__ xcr, float* __restrict__ zb){
  __shared__ float xn[16*NP];
  const int tok0 = blockIdx.x * 16;
  {
    const int j = threadIdx.x >> 4;     // token in block
    const int l16 = threadIdx.x & 15;
    const float* sp = seq + ((size_t)(tok0 + j))*NF;
    float v[8]; float s = 0.f, s2 = 0.f;
    #pragma unroll
    for (int i = 0; i < 8; ++i){ float f = sp[l16 + 16*i]; v[i] = f; s += f; s2 += f*f; }
    #pragma unroll
    for (int m = 1; m < 16; m <<= 1){ s += __shfl_xor(s, m, 64); s2 += __shfl_xor(s2, m, 64); }
    const float mean = s * (1.f/128.f);
    const float rstd = rsqrtf(s2*(1.f/128.f) - mean*mean + 1e-5f);
    #pragma unroll
    for (int i = 0; i < 8; ++i){
      int n = l16 + 16*i;
      xn[j*NP + n] = (v[i]-mean)*rstd*lnw[n] + lnb[n];
    }
  }
  __syncthreads();
  // thread -> output cols {c, c+128}, token group g (8 tokens); wave-uniform g => LDS broadcast
  const int c = threadIdx.x & 127, g = threadIdx.x >> 7;
  const float4* wr0 = (const float4*)(iw + (size_t)c*NF);
  const float4* wr1 = (const float4*)(iw + (size_t)(c + NF)*NF);
  float acc0[8], acc1[8];
  #pragma unroll
  for (int i = 0; i < 8; ++i){ acc0[i] = 0.f; acc1[i] = 0.f; }
  for (int k4 = 0; k4 < 32; ++k4){
    float4 w0 = wr0[k4], w1 = wr1[k4];
    #pragma unroll
    for (int i = 0; i < 8; ++i){
      float4 x4 = *((const float4*)&xn[(g*8 + i)*NP + k4*4]);   // broadcast
      acc0[i] = fmaf(w0.x,x4.x, fmaf(w0.y,x4.y, fmaf(w0.z,x4.z, fmaf(w0.w,x4.w, acc0[i]))));
      acc1[i] = fmaf(w1.x,x4.x, fmaf(w1.y,x4.y, fmaf(w1.z,x4.z, fmaf(w1.w,x4.w, acc1[i]))));
    }
  }
  const float b0 = ib[c], b1 = ib[c + NF];
  #pragma unroll
  for (int i = 0; i < 8; ++i){
    size_t tok = (size_t)(tok0 + g*8 + i);
    xcr[tok*NF + c] = acc0[i] + b0;
    zb [tok*NF + c] = acc1[i] + b1;
  }
}

// ---- K2: 40 tokens/block. conv(DC=4)+silu -> x-proj(32xN) -> dt/B/C.
__global__ __launch_bounds__(256) void k_conv_dt(
    const float* __restrict__ xcr,
    const float* __restrict__ cw, const float* __restrict__ cb,
    const float* __restrict__ xw, const float* __restrict__ dw, const float* __restrict__ db,
    float* __restrict__ xcc, float* __restrict__ dtb,
    float* __restrict__ Bmb, float* __restrict__ Cmb){
  __shared__ float sxr[(CLEN+3)*NF];   // rows 0..42 = tokens t0-3 .. t0+39
  __shared__ float sxc[CLEN*NF];       // conv+silu result
  __shared__ float sdbc[CLEN*32];      // x-proj output (dt-rank 8, B 12, C 12)
  const int sq = blockIdx.x / NCH, cblk = blockIdx.x - sq*NCH;
  const int t0 = cblk*CLEN;
  const int tid = threadIdx.x;

  for (int e = tid; e < (CLEN+3)*NF; e += 256){
    int r = e >> 7, n = e & 127;
    int t = t0 - 3 + r;
    sxr[e] = (t >= 0) ? xcr[((size_t)sq*TL + t)*NF + n] : 0.f;
  }
  __syncthreads();

  #pragma unroll
  for (int i = 0; i < (CLEN*NF)/256; ++i){
    int e = tid + i*256;
    int r = e >> 7, n = e & 127;
    float a = cb[n];
    #pragma unroll
    for (int k = 0; k < 4; ++k)
      a = fmaf(sxr[(r+k)*NF + n], cw[n*4 + k], a);
    float v = siluf(a);
    sxc[e] = v;
    xcc[((size_t)sq*TL + t0)*NF + e] = v;
  }
  __syncthreads();

  {
    const int o = tid & 31, jg = tid >> 5;
    const float4* wr = (const float4*)(xw + (size_t)o*NF);
    float acc[5];
    #pragma unroll
    for (int j = 0; j < 5; ++j) acc[j] = 0.f;
    for (int k4 = 0; k4 < 32; ++k4){
      float4 w4 = wr[k4];
      #pragma unroll
      for (int j = 0; j < 5; ++j){
        float4 x4 = *((const float4*)&sxc[(jg*5 + j)*NF + k4*4]);
        acc[j] = fmaf(w4.x,x4.x, fmaf(w4.y,x4.y, fmaf(w4.z,x4.z, fmaf(w4.w,x4.w, acc[j]))));
      }
    }
    #pragma unroll
    for (int j = 0; j < 5; ++j) sdbc[(jg*5 + j)*32 + o] = acc[j];
  }
  __syncthreads();

  #pragma unroll
  for (int i = 0; i < (CLEN*NF)/256; ++i){
    int e = tid + i*256;
    int r = e >> 7, n = e & 127;
    float acc = db[n];
    #pragma unroll
    for (int q = 0; q < 8; ++q)
      acc = fmaf(sdbc[r*32 + q], dw[n*8 + q], acc);
    dtb[((size_t)sq*TL + t0)*NF + e] = softplusf(acc);
  }
  for (int e = tid; e < CLEN*2*SD; e += 256){
    int r = e / (2*SD), c = e - r*2*SD;
    float v = sdbc[r*32 + 8 + c];
    size_t tok = (size_t)sq*TL + t0 + r;
    if (c < SD) Bmb[tok*SD + c] = v;
    else        Cmb[tok*SD + (c - SD)] = v;
  }
}

// ---- K3a: scan pass 1
__global__ __launch_bounds__(128) void k_scan_pass1(
    const float* __restrict__ dtb, const float* __restrict__ xcc,
    const float* __restrict__ Bmb, const float* __restrict__ alog,
    float* __restrict__ ap, float* __restrict__ hfb){
  const int bid = blockIdx.x;
  const int sq = bid / NCH, c = bid - sq*NCH;
  const int n = threadIdx.x;
  const float4* A4 = (const float4*)(alog + (size_t)n*SD);
  float4 Aa = A4[0], Ab = A4[1], Ac = A4[2];
  float Av[SD] = {Aa.x,Aa.y,Aa.z,Aa.w, Ab.x,Ab.y,Ab.z,Ab.w, Ac.x,Ac.y,Ac.z,Ac.w};
  #pragma unroll
  for (int s = 0; s < SD; ++s) Av[s] = -__expf(Av[s]);
  float h[SD], apv[SD];
  #pragma unroll
  for (int s = 0; s < SD; ++s){ h[s] = 0.f; apv[s] = 1.f; }
  const size_t tok0 = (size_t)sq*TL + c*CLEN;
  for (int tt = 0; tt < CLEN; ++tt){
    const size_t tok = tok0 + tt;
    float dtv = dtb[tok*NF + n];
    float dx  = dtv * xcc[tok*NF + n];
    const float4* B4 = (const float4*)(Bmb + tok*SD);
    float4 Ba = B4[0], Bb = B4[1], Bc = B4[2];
    float Bv[SD] = {Ba.x,Ba.y,Ba.z,Ba.w, Bb.x,Bb.y,Bb.z,Bb.w, Bc.x,Bc.y,Bc.z,Bc.w};
    #pragma unroll
    for (int s = 0; s < SD; ++s){
      float dA = __expf(dtv*Av[s]);
      h[s] = fmaf(dA, h[s], dx*Bv[s]);
      apv[s] *= dA;
    }
  }
  const size_t base = (size_t)bid*SD*NF + n;
  #pragma unroll
  for (int s = 0; s < SD; ++s){ ap[base + s*NF] = apv[s]; hfb[base + s*NF] = h[s]; }
}

// ---- K3b: sequential combine across chunks
__global__ __launch_bounds__(128) void k_scan_combine(
    const float* __restrict__ ap, const float* __restrict__ hfb, float* __restrict__ hinit){
  const int sq = blockIdx.x;
  const int n = threadIdx.x;
  float h[SD];
  #pragma unroll
  for (int s = 0; s < SD; ++s) h[s] = 0.f;
  for (int c = 0; c < NCH; ++c){
    const size_t base = ((size_t)sq*NCH + c)*SD*NF + n;
    #pragma unroll
    for (int s = 0; s < SD; ++s){
      hinit[base + s*NF] = h[s];
      h[s] = fmaf(ap[base + s*NF], h[s], hfb[base + s*NF]);
    }
  }
}

// ---- K3c: scan pass 2
__global__ __launch_bounds__(128) void k_scan_pass2(
    const float* __restrict__ dtb, const float* __restrict__ xcc,
    const float* __restrict__ Bmb, const float* __restrict__ Cmb,
    const float* __restrict__ alog, const float* __restrict__ hinit,
    float* __restrict__ yb){
  const int bid = blockIdx.x;
  const int sq = bid / NCH, c = bid - sq*NCH;
  const int n = threadIdx.x;
  const float4* A4 = (const float4*)(alog + (size_t)n*SD);
  float4 Aa = A4[0], Ab = A4[1], Ac = A4[2];
  float Av[SD] = {Aa.x,Aa.y,Aa.z,Aa.w, Ab.x,Ab.y,Ab.z,Ab.w, Ac.x,Ac.y,Ac.z,Ac.w};
  #pragma unroll
  for (int s = 0; s < SD; ++s) Av[s] = -__expf(Av[s]);
  float h[SD];
  const size_t hbase = (size_t)bid*SD*NF + n;
  #pragma unroll
  for (int s = 0; s < SD; ++s) h[s] = hinit[hbase + s*NF];
  const size_t tok0 = (size_t)sq*TL + c*CLEN;
  for (int tt = 0; tt < CLEN; ++tt){
    const size_t tok = tok0 + tt;
    float dtv = dtb[tok*NF + n];
    float dx  = dtv * xcc[tok*NF + n];
    const float4* B4 = (const float4*)(Bmb + tok*SD);
    const float4* C4 = (const float4*)(Cmb + tok*SD);
    float4 Ba=B4[0], Bb=B4[1], Bc=B4[2];
    float4 Ca=C4[0], Cb=C4[1], Cc=C4[2];
    float Bv[SD] = {Ba.x,Ba.y,Ba.z,Ba.w, Bb.x,Bb.y,Bb.z,Bb.w, Bc.x,Bc.y,Bc.z,Bc.w};
    float Cv[SD] = {Ca.x,Ca.y,Ca.z,Ca.w, Cb.x,Cb.y,Cb.z,Cb.w, Cc.x,Cc.y,Cc.z,Cc.w};
    float yv = 0.f;
    #pragma unroll
    for (int s = 0; s < SD; ++s){
      float dA = __expf(dtv*Av[s]);
      h[s] = fmaf(dA, h[s], dx*Bv[s]);
      yv = fmaf(h[s], Cv[s], yv);
    }
    yb[tok*NF + n] = yv;
  }
}

// ---- K4: y2 = (y + Dv*xc)*silu(z); seq += y2 @ ow^T + ob. 32 tokens/block, 2 cols/thread
__global__ __launch_bounds__(256) void k_gate_out(
    const float* __restrict__ yb, const float* __restrict__ xcc, const float* __restrict__ zb,
    const float* __restrict__ Dv, const float* __restrict__ ow, const float* __restrict__ ob,
    float* __restrict__ seq){
  __shared__ float sy[32*NP];
  const int tok0 = blockIdx.x * 32;
  for (int e = threadIdx.x; e < 32*NF; e += 256){
    int r = e >> 7, n = e & 127;
    size_t idx = (size_t)tok0*NF + e;
    float yv = fmaf(Dv[n], xcc[idx], yb[idx]);
    sy[r*NP + n] = yv * siluf(zb[idx]);
  }
  __syncthreads();
  // cols {c, c+64}, token group g of 8 (wave-uniform g => broadcast LDS reads)
  const int c = threadIdx.x & 63, g = threadIdx.x >> 6;
  const float4* wr0 = (const float4*)(ow + (size_t)c*NF);
  const float4* wr1 = (const float4*)(ow + (size_t)(c + 64)*NF);
  float acc0[8], acc1[8];
  #pragma unroll
  for (int i = 0; i < 8; ++i){ acc0[i] = 0.f; acc1[i] = 0.f; }
  for (int k4 = 0; k4 < 32; ++k4){
    float4 w0 = wr0[k4], w1 = wr1[k4];
    #pragma unroll
    for (int i = 0; i < 8; ++i){
      float4 x4 = *((const float4*)&sy[(g*8 + i)*NP + k4*4]);
      acc0[i] = fmaf(w0.x,x4.x, fmaf(w0.y,x4.y, fmaf(w0.z,x4.z, fmaf(w0.w,x4.w, acc0[i]))));
      acc1[i] = fmaf(w1.x,x4.x, fmaf(w1.y,x4.y, fmaf(w1.z,x4.z, fmaf(w1.w,x4.w, acc1[i]))));
    }
  }
  const float b0 = ob[c], b1 = ob[c + 64];
  #pragma unroll
  for (int i = 0; i < 8; ++i){
    size_t tok = (size_t)(tok0 + g*8 + i);
    seq[tok*NF + c]      += acc0[i] + b0;
    seq[tok*NF + c + 64] += acc1[i] + b1;
  }
}

// ---- K5: cross block + final LN + transpose; one block per (b,t)
__global__ __launch_bounds__(256) void k_cross_final(
    const float* __restrict__ seq,
    const float* __restrict__ cbw, const float* __restrict__ cbb,
    const float* __restrict__ clnw, const float* __restrict__ clnb,
    const float* __restrict__ flnw, const float* __restrict__ flnb,
    float* __restrict__ out){
  const int b = blockIdx.x / TL, t = blockIdx.x % TL;
  __shared__ float Sm[30*NP];
  __shared__ float Cx[30*NP];
  __shared__ float mu[30], rsd[30];
  const int tid = threadIdx.x;
  for (int e = tid; e < 30*NF; e += 256){
    int k = e >> 7, n = e & 127;
    Sm[k*NP + n] = seq[((size_t)(b*30 + k)*TL + t)*NF + n];
  }
  __syncthreads();
  // cross matmul: thread owns col n for rows k = kb, kb+2, ... (15 rows)
  {
    const int n = tid & 127, kb = tid >> 7;
    const float4* wr = (const float4*)(cbw + (size_t)n*NF);
    float acc[15];
    #pragma unroll
    for (int i = 0; i < 15; ++i) acc[i] = 0.f;
    for (int k4 = 0; k4 < 32; ++k4){
      float4 w4 = wr[k4];
      #pragma unroll
      for (int i = 0; i < 15; ++i){
        float4 x4 = *((const float4*)&Sm[(kb + 2*i)*NP + k4*4]);  // broadcast
        acc[i] = fmaf(w4.x,x4.x, fmaf(w4.y,x4.y, fmaf(w4.z,x4.z, fmaf(w4.w,x4.w, acc[i]))));
      }
    }
    const float bb = cbb[n];
    #pragma unroll
    for (int i = 0; i < 15; ++i) Cx[(kb + 2*i)*NP + n] = acc[i] + bb;
  }
  __syncthreads();
  // LN over Cx rows: wave-parallel (wave w does rows w, w+4, ...)
  {
    const int w = tid >> 6, lane = tid & 63;
    for (int r = w; r < 30; r += 4){
      float2 v = *((const float2*)&Cx[r*NP + lane*2]);
      float s = v.x + v.y, s2 = v.x*v.x + v.y*v.y;
      #pragma unroll
      for (int m = 1; m < 64; m <<= 1){ s += __shfl_xor(s, m, 64); s2 += __shfl_xor(s2, m, 64); }
      if (lane == 0){
        float mm = s * (1.f/128.f);
        mu[r] = mm; rsd[r] = rsqrtf(s2*(1.f/128.f) - mm*mm + 1e-5f);
      }
    }
  }
  __syncthreads();
  for (int e = tid; e < 30*NF; e += 256){
    int k = e >> 7, n = e & 127;
    float cn = (Cx[k*NP + n] - mu[k])*rsd[k]*clnw[n] + clnb[n];
    float g = 0.5f*cn*(1.f + erff(cn*0.70710678118f));   // exact gelu
    Cx[k*NP + n] = Sm[k*NP + n] + g;
  }
  __syncthreads();
  {
    const int w = tid >> 6, lane = tid & 63;
    for (int r = w; r < 30; r += 4){
      float2 v = *((const float2*)&Cx[r*NP + lane*2]);
      float s = v.x + v.y, s2 = v.x*v.x + v.y*v.y;
      #pragma unroll
      for (int m = 1; m < 64; m <<= 1){ s += __shfl_xor(s, m, 64); s2 += __shfl_xor(s2, m, 64); }
      if (lane == 0){
        float mm = s * (1.f/128.f);
        mu[r] = mm; rsd[r] = rsqrtf(s2*(1.f/128.f) - mm*mm + 1e-5f);
      }
    }
  }
  __syncthreads();
  for (int e = tid; e < 30*NF; e += 256){
    int n = e / 30, k = e - n*30;   // k fastest for coalesced write
    float v = (Cx[k*NP + n] - mu[k])*rsd[k]*flnw[n] + flnb[n];
    out[((size_t)(b*NF + n)*TL + t)*30 + k] = v;
  }
}

extern "C" void kernel_launch(void* const* d_in, const int* in_sizes, int n_in,
                              void* d_out, int out_size, void* d_ws, size_t ws_size,
                              hipStream_t stream){
  const float* x       = (const float*)d_in[0];
  const float* ln_w    = (const float*)d_in[1];
  const float* ln_b    = (const float*)d_in[2];
  const float* in_w    = (const float*)d_in[3];
  const float* in_b    = (const float*)d_in[4];
  const float* conv_w  = (const float*)d_in[5];
  const float* conv_b  = (const float*)d_in[6];
  const float* xp_w    = (const float*)d_in[7];
  const float* dtp_w   = (const float*)d_in[8];
  const float* dtp_b   = (const float*)d_in[9];
  const float* A_log   = (const float*)d_in[10];
  const float* Dv      = (const float*)d_in[11];
  const float* out_w   = (const float*)d_in[12];
  const float* out_b   = (const float*)d_in[13];
  const float* cb_w    = (const float*)d_in[14];
  const float* cb_b    = (const float*)d_in[15];
  const float* cb_ln_w = (const float*)d_in[16];
  const float* cb_ln_b = (const float*)d_in[17];
  const float* fin_ln_w= (const float*)d_in[18];
  const float* fin_ln_b= (const float*)d_in[19];
  float* out = (float*)d_out;

  const size_t SEQSZ = (size_t)BKS*TL*NF;
  const size_t CHSZ  = (size_t)BKS*NF*NCH*SD;
  float* ws  = (float*)d_ws;
  float* seq = ws;
  float* xcr = ws + SEQSZ;        // dead after k_conv_dt -> reused for scan scratch
  float* zb  = ws + 2*SEQSZ;
  float* xcc = ws + 3*SEQSZ;
  float* dtb = ws + 4*SEQSZ;
  float* yb  = ws + 5*SEQSZ;
  float* Bmb = ws + 6*SEQSZ;
  float* Cmb = Bmb + (size_t)BKS*TL*SD;
  float* ap    = xcr;
  float* hfb   = xcr + CHSZ;
  float* hinit = xcr + 2*CHSZ;
  if (ws_size < (6*SEQSZ + 2*(size_t)BKS*TL*SD)*sizeof(float)) return;

  k_ingest<<<2*TL, 256, 0, stream>>>(x, seq);
  for (int l = 0; l < 4; ++l){
    k_ln_inproj<<<NTOK/16, 256, 0, stream>>>(seq, ln_w + l*NF, ln_b + l*NF,
        in_w + (size_t)l*2*NF*NF, in_b + l*2*NF, xcr, zb);
    k_conv_dt<<<BKS*NCH, 256, 0, stream>>>(xcr, conv_w + (size_t)l*NF*4, conv_b + l*NF,
        xp_w + (size_t)l*32*NF, dtp_w + (size_t)l*NF*RD, dtp_b + l*NF, xcc, dtb, Bmb, Cmb);
    k_scan_pass1<<<BKS*NCH, NF, 0, stream>>>(dtb, xcc, Bmb, A_log + (size_t)l*NF*SD, ap, hfb);
    k_scan_combine<<<BKS, NF, 0, stream>>>(ap, hfb, hinit);
    k_scan_pass2<<<BKS*NCH, NF, 0, stream>>>(dtb, xcc, Bmb, Cmb, A_log + (size_t)l*NF*SD, hinit, yb);
    k_gate_out<<<NTOK/32, 256, 0, stream>>>(yb, xcc, zb, Dv + l*NF,
        out_w + (size_t)l*NF*NF, out_b + l*NF, seq);
  }
  k_cross_final<<<2*TL, 256, 0, stream>>>(seq, cb_w, cb_b, cb_ln_w, cb_ln_b, fin_ln_w, fin_ln_b, out);
}

// Round 4
// 1139.958 us; speedup vs baseline: 1.3165x; 1.3165x over previous
//
#include <hip/hip_runtime.h>
#include <math.h>

#define BKS 60      // B*K sequences
#define TL  1000    // T
#define NF  128     // N features
#define NP  132     // padded LDS row stride (cross_final)
#define SD  12      // state dim S
#define RD  8       // dt rank
#define NCH 25      // scan chunks
#define CLEN 40     // chunk length (NCH*CLEN == TL)
#define NTOK (BKS*TL)
#define MT  64      // GEMM token tile
#define NBLK ((NTOK + MT - 1)/MT)   // 938
#define XSP 68      // xs transposed stride: (4n+t)%32 -> 2-way max
#define WSP 260     // in_proj w_lds stride (256+4)
#define GWS 132     // gate_out w_lds stride (128+4)

__device__ __forceinline__ float siluf(float x){ return x / (1.f + __expf(-x)); }
__device__ __forceinline__ float softplusf(float x){
  if (x > 20.f) return x;
  float e = __expf(x);
  return (x < -20.f) ? e : __logf(1.f + e);
}

// ---- K0: x (B,N,T,K) -> seq (B*K, T, N), one block per (b,t)
__global__ __launch_bounds__(256) void k_ingest(const float* __restrict__ x, float* __restrict__ seq){
  const int b = blockIdx.x / TL, t = blockIdx.x % TL;
  __shared__ float tile[30*NF];
  for (int e = threadIdx.x; e < 30*NF; e += 256){
    int n = e / 30, k = e - n*30;
    tile[k*NF + n] = x[((size_t)(b*NF + n)*TL + t)*30 + k];
  }
  __syncthreads();
  const size_t base = ((size_t)b*30)*TL*NF + (size_t)t*NF;
  for (int e = threadIdx.x; e < 30*NF; e += 256){
    int k = e >> 7, n = e & 127;
    seq[base + (size_t)k*TL*NF + n] = tile[e];
  }
}

// ---- K1: LayerNorm + in_proj. 64 tokens/block, weights staged in LDS (k-tiled),
// LN output transposed in LDS; thread computes 8 outs x 8 tokens.
__global__ __launch_bounds__(256) void k_ln_inproj(
    const float* __restrict__ seq, const float* __restrict__ lnw, const float* __restrict__ lnb,
    const float* __restrict__ iw, const float* __restrict__ ib,
    float* __restrict__ xcr, float* __restrict__ zb){
  __shared__ float xs[NF*XSP];    // [k][t]  34816 B
  __shared__ float wl[16*WSP];    // [kl][o] 16640 B
  const int tid = threadIdx.x;
  const int tok0 = blockIdx.x * MT;

  // LN phase: 4 iterations x 16 tokens; 16 lanes per token
  {
    const int j = tid >> 4, l16 = tid & 15;
    for (int it = 0; it < 4; ++it){
      const int t = j + 16*it;
      const int tok = tok0 + t;
      float v[8]; float s = 0.f, s2 = 0.f;
      if (tok < NTOK){
        const float* sp = seq + (size_t)tok*NF;
        #pragma unroll
        for (int i = 0; i < 8; ++i){ float f = sp[l16 + 16*i]; v[i] = f; s += f; s2 += f*f; }
      } else {
        #pragma unroll
        for (int i = 0; i < 8; ++i) v[i] = 0.f;
      }
      #pragma unroll
      for (int m = 1; m < 16; m <<= 1){ s += __shfl_xor(s, m, 64); s2 += __shfl_xor(s2, m, 64); }
      const float mean = s * (1.f/128.f);
      const float rstd = rsqrtf(s2*(1.f/128.f) - mean*mean + 1e-5f);
      #pragma unroll
      for (int i = 0; i < 8; ++i){
        int n = l16 + 16*i;
        xs[n*XSP + t] = (v[i]-mean)*rstd*lnw[n] + lnb[n];
      }
    }
  }

  const int o8 = tid & 31, t8 = tid >> 5;   // 32 out-groups x 8, 8 token-groups x 8
  float acc[8][8];
  #pragma unroll
  for (int o = 0; o < 8; ++o)
    #pragma unroll
    for (int t = 0; t < 8; ++t) acc[o][t] = 0.f;

  for (int kt = 0; kt < 8; ++kt){
    __syncthreads();
    // stage w tile: rows o=0..255, k = kt*16..+15, transposed into [kl][o]
    {
      const int ch = tid & 3, row = tid >> 2;   // 4 chunks of 4 k, 64 rows/pass
      #pragma unroll
      for (int p = 0; p < 4; ++p){
        const int o = row + 64*p;
        const float4 w4 = *(const float4*)(iw + (size_t)o*NF + kt*16 + ch*4);
        const int kl = ch*4;
        wl[(kl+0)*WSP + o] = w4.x;
        wl[(kl+1)*WSP + o] = w4.y;
        wl[(kl+2)*WSP + o] = w4.z;
        wl[(kl+3)*WSP + o] = w4.w;
      }
    }
    __syncthreads();
    for (int kl = 0; kl < 16; ++kl){
      const int kg = kt*16 + kl;
      const float4 wa = *(const float4*)&wl[kl*WSP + o8*8];
      const float4 wb = *(const float4*)&wl[kl*WSP + o8*8 + 4];
      const float4 xa = *(const float4*)&xs[kg*XSP + t8*8];
      const float4 xb = *(const float4*)&xs[kg*XSP + t8*8 + 4];
      const float wv[8] = {wa.x,wa.y,wa.z,wa.w, wb.x,wb.y,wb.z,wb.w};
      const float xv[8] = {xa.x,xa.y,xa.z,xa.w, xb.x,xb.y,xb.z,xb.w};
      #pragma unroll
      for (int o = 0; o < 8; ++o)
        #pragma unroll
        for (int t = 0; t < 8; ++t)
          acc[o][t] = fmaf(wv[o], xv[t], acc[o][t]);
    }
  }

  // epilogue
  float bo[8];
  #pragma unroll
  for (int i = 0; i < 8; ++i) bo[i] = ib[o8*8 + i];
  #pragma unroll
  for (int j = 0; j < 8; ++j){
    const int tok = tok0 + t8*8 + j;
    if (tok >= NTOK) break;
    float4 r0, r1;
    r0.x = acc[0][j]+bo[0]; r0.y = acc[1][j]+bo[1]; r0.z = acc[2][j]+bo[2]; r0.w = acc[3][j]+bo[3];
    r1.x = acc[4][j]+bo[4]; r1.y = acc[5][j]+bo[5]; r1.z = acc[6][j]+bo[6]; r1.w = acc[7][j]+bo[7];
    if (o8 < 16){
      float* dst = xcr + (size_t)tok*NF + o8*8;
      *(float4*)dst = r0; *(float4*)(dst+4) = r1;
    } else {
      float* dst = zb + (size_t)tok*NF + (o8*8 - 128);
      *(float4*)dst = r0; *(float4*)(dst+4) = r1;
    }
  }
}

// ---- K2: 40 tokens/block. conv(DC=4)+silu -> x-proj(32xN) -> dt/B/C.
__global__ __launch_bounds__(256) void k_conv_dt(
    const float* __restrict__ xcr,
    const float* __restrict__ cw, const float* __restrict__ cb,
    const float* __restrict__ xw, const float* __restrict__ dw, const float* __restrict__ db,
    float* __restrict__ xcc, float* __restrict__ dtb,
    float* __restrict__ Bmb, float* __restrict__ Cmb){
  __shared__ float sxr[(CLEN+3)*NF];
  __shared__ float sxc[CLEN*NF];
  __shared__ float sdbc[CLEN*32];
  const int sq = blockIdx.x / NCH, cblk = blockIdx.x - sq*NCH;
  const int t0 = cblk*CLEN;
  const int tid = threadIdx.x;

  for (int e = tid; e < (CLEN+3)*NF; e += 256){
    int r = e >> 7, n = e & 127;
    int t = t0 - 3 + r;
    sxr[e] = (t >= 0) ? xcr[((size_t)sq*TL + t)*NF + n] : 0.f;
  }
  __syncthreads();

  #pragma unroll
  for (int i = 0; i < (CLEN*NF)/256; ++i){
    int e = tid + i*256;
    int r = e >> 7, n = e & 127;
    float a = cb[n];
    #pragma unroll
    for (int k = 0; k < 4; ++k)
      a = fmaf(sxr[(r+k)*NF + n], cw[n*4 + k], a);
    float v = siluf(a);
    sxc[e] = v;
    xcc[((size_t)sq*TL + t0)*NF + e] = v;
  }
  __syncthreads();

  {
    const int o = tid & 31, jg = tid >> 5;
    const float4* wr = (const float4*)(xw + (size_t)o*NF);
    float acc[5];
    #pragma unroll
    for (int j = 0; j < 5; ++j) acc[j] = 0.f;
    for (int k4 = 0; k4 < 32; ++k4){
      float4 w4 = wr[k4];
      #pragma unroll
      for (int j = 0; j < 5; ++j){
        float4 x4 = *((const float4*)&sxc[(jg*5 + j)*NF + k4*4]);
        acc[j] = fmaf(w4.x,x4.x, fmaf(w4.y,x4.y, fmaf(w4.z,x4.z, fmaf(w4.w,x4.w, acc[j]))));
      }
    }
    #pragma unroll
    for (int j = 0; j < 5; ++j) sdbc[(jg*5 + j)*32 + o] = acc[j];
  }
  __syncthreads();

  #pragma unroll
  for (int i = 0; i < (CLEN*NF)/256; ++i){
    int e = tid + i*256;
    int r = e >> 7, n = e & 127;
    float acc = db[n];
    #pragma unroll
    for (int q = 0; q < 8; ++q)
      acc = fmaf(sdbc[r*32 + q], dw[n*8 + q], acc);
    dtb[((size_t)sq*TL + t0)*NF + e] = softplusf(acc);
  }
  for (int e = tid; e < CLEN*2*SD; e += 256){
    int r = e / (2*SD), c = e - r*2*SD;
    float v = sdbc[r*32 + 8 + c];
    size_t tok = (size_t)sq*TL + t0 + r;
    if (c < SD) Bmb[tok*SD + c] = v;
    else        Cmb[tok*SD + (c - SD)] = v;
  }
}

// ---- K3a: scan pass 1
__global__ __launch_bounds__(128) void k_scan_pass1(
    const float* __restrict__ dtb, const float* __restrict__ xcc,
    const float* __restrict__ Bmb, const float* __restrict__ alog,
    float* __restrict__ ap, float* __restrict__ hfb){
  const int bid = blockIdx.x;
  const int sq = bid / NCH, c = bid - sq*NCH;
  const int n = threadIdx.x;
  const float4* A4 = (const float4*)(alog + (size_t)n*SD);
  float4 Aa = A4[0], Ab = A4[1], Ac = A4[2];
  float Av[SD] = {Aa.x,Aa.y,Aa.z,Aa.w, Ab.x,Ab.y,Ab.z,Ab.w, Ac.x,Ac.y,Ac.z,Ac.w};
  #pragma unroll
  for (int s = 0; s < SD; ++s) Av[s] = -__expf(Av[s]);
  float h[SD], apv[SD];
  #pragma unroll
  for (int s = 0; s < SD; ++s){ h[s] = 0.f; apv[s] = 1.f; }
  const size_t tok0 = (size_t)sq*TL + c*CLEN;
  for (int tt = 0; tt < CLEN; ++tt){
    const size_t tok = tok0 + tt;
    float dtv = dtb[tok*NF + n];
    float dx  = dtv * xcc[tok*NF + n];
    const float4* B4 = (const float4*)(Bmb + tok*SD);
    float4 Ba = B4[0], Bb = B4[1], Bc = B4[2];
    float Bv[SD] = {Ba.x,Ba.y,Ba.z,Ba.w, Bb.x,Bb.y,Bb.z,Bb.w, Bc.x,Bc.y,Bc.z,Bc.w};
    #pragma unroll
    for (int s = 0; s < SD; ++s){
      float dA = __expf(dtv*Av[s]);
      h[s] = fmaf(dA, h[s], dx*Bv[s]);
      apv[s] *= dA;
    }
  }
  const size_t base = (size_t)bid*SD*NF + n;
  #pragma unroll
  for (int s = 0; s < SD; ++s){ ap[base + s*NF] = apv[s]; hfb[base + s*NF] = h[s]; }
}

// ---- K3b: sequential combine across chunks
__global__ __launch_bounds__(128) void k_scan_combine(
    const float* __restrict__ ap, const float* __restrict__ hfb, float* __restrict__ hinit){
  const int sq = blockIdx.x;
  const int n = threadIdx.x;
  float h[SD];
  #pragma unroll
  for (int s = 0; s < SD; ++s) h[s] = 0.f;
  for (int c = 0; c < NCH; ++c){
    const size_t base = ((size_t)sq*NCH + c)*SD*NF + n;
    #pragma unroll
    for (int s = 0; s < SD; ++s){
      hinit[base + s*NF] = h[s];
      h[s] = fmaf(ap[base + s*NF], h[s], hfb[base + s*NF]);
    }
  }
}

// ---- K3c: scan pass 2
__global__ __launch_bounds__(128) void k_scan_pass2(
    const float* __restrict__ dtb, const float* __restrict__ xcc,
    const float* __restrict__ Bmb, const float* __restrict__ Cmb,
    const float* __restrict__ alog, const float* __restrict__ hinit,
    float* __restrict__ yb){
  const int bid = blockIdx.x;
  const int sq = bid / NCH, c = bid - sq*NCH;
  const int n = threadIdx.x;
  const float4* A4 = (const float4*)(alog + (size_t)n*SD);
  float4 Aa = A4[0], Ab = A4[1], Ac = A4[2];
  float Av[SD] = {Aa.x,Aa.y,Aa.z,Aa.w, Ab.x,Ab.y,Ab.z,Ab.w, Ac.x,Ac.y,Ac.z,Ac.w};
  #pragma unroll
  for (int s = 0; s < SD; ++s) Av[s] = -__expf(Av[s]);
  float h[SD];
  const size_t hbase = (size_t)bid*SD*NF + n;
  #pragma unroll
  for (int s = 0; s < SD; ++s) h[s] = hinit[hbase + s*NF];
  const size_t tok0 = (size_t)sq*TL + c*CLEN;
  for (int tt = 0; tt < CLEN; ++tt){
    const size_t tok = tok0 + tt;
    float dtv = dtb[tok*NF + n];
    float dx  = dtv * xcc[tok*NF + n];
    const float4* B4 = (const float4*)(Bmb + tok*SD);
    const float4* C4 = (const float4*)(Cmb + tok*SD);
    float4 Ba=B4[0], Bb=B4[1], Bc=B4[2];
    float4 Ca=C4[0], Cb=C4[1], Cc=C4[2];
    float Bv[SD] = {Ba.x,Ba.y,Ba.z,Ba.w, Bb.x,Bb.y,Bb.z,Bb.w, Bc.x,Bc.y,Bc.z,Bc.w};
    float Cv[SD] = {Ca.x,Ca.y,Ca.z,Ca.w, Cb.x,Cb.y,Cb.z,Cb.w, Cc.x,Cc.y,Cc.z,Cc.w};
    float yv = 0.f;
    #pragma unroll
    for (int s = 0; s < SD; ++s){
      float dA = __expf(dtv*Av[s]);
      h[s] = fmaf(dA, h[s], dx*Bv[s]);
      yv = fmaf(h[s], Cv[s], yv);
    }
    yb[tok*NF + n] = yv;
  }
}

// ---- K4: y2 = (y + Dv*xc)*silu(z); seq += y2 @ ow^T + ob. 64 tokens/block, tiled GEMM.
__global__ __launch_bounds__(256) void k_gate_out(
    const float* __restrict__ yb, const float* __restrict__ xcc, const float* __restrict__ zb,
    const float* __restrict__ Dv, const float* __restrict__ ow, const float* __restrict__ ob,
    float* __restrict__ seq){
  __shared__ float xs[NF*XSP];    // [n][t] transposed gated activations
  __shared__ float wl[32*GWS];    // [kl][o] 16896 B
  const int tid = threadIdx.x;
  const int tok0 = blockIdx.x * MT;

  // elementwise gate, write transposed
  #pragma unroll
  for (int i = 0; i < 32; ++i){
    const int e = tid + i*256;
    const int r = e >> 7, n = e & 127;
    const int tok = tok0 + r;
    float g = 0.f;
    if (tok < NTOK){
      const size_t idx = (size_t)tok*NF + n;
      float yv = fmaf(Dv[n], xcc[idx], yb[idx]);
      g = yv * siluf(zb[idx]);
    }
    xs[n*XSP + r] = g;
  }

  const int o4 = tid & 31, t8 = tid >> 5;   // 32 out-groups x 4, 8 token-groups x 8
  float acc[4][8];
  #pragma unroll
  for (int o = 0; o < 4; ++o)
    #pragma unroll
    for (int t = 0; t < 8; ++t) acc[o][t] = 0.f;

  for (int kt = 0; kt < 4; ++kt){
    __syncthreads();
    {
      const int ch = tid & 7, row = tid >> 3;   // 8 chunks of 4 k, 32 rows/pass
      #pragma unroll
      for (int p = 0; p < 4; ++p){
        const int o = row + 32*p;
        const float4 w4 = *(const float4*)(ow + (size_t)o*NF + kt*32 + ch*4);
        const int kl = ch*4;
        wl[(kl+0)*GWS + o] = w4.x;
        wl[(kl+1)*GWS + o] = w4.y;
        wl[(kl+2)*GWS + o] = w4.z;
        wl[(kl+3)*GWS + o] = w4.w;
      }
    }
    __syncthreads();
    for (int kl = 0; kl < 32; ++kl){
      const int kg = kt*32 + kl;
      const float4 wa = *(const float4*)&wl[kl*GWS + o4*4];
      const float4 xa = *(const float4*)&xs[kg*XSP + t8*8];
      const float4 xb = *(const float4*)&xs[kg*XSP + t8*8 + 4];
      const float wv[4] = {wa.x,wa.y,wa.z,wa.w};
      const float xv[8] = {xa.x,xa.y,xa.z,xa.w, xb.x,xb.y,xb.z,xb.w};
      #pragma unroll
      for (int o = 0; o < 4; ++o)
        #pragma unroll
        for (int t = 0; t < 8; ++t)
          acc[o][t] = fmaf(wv[o], xv[t], acc[o][t]);
    }
  }

  float bo[4];
  #pragma unroll
  for (int i = 0; i < 4; ++i) bo[i] = ob[o4*4 + i];
  #pragma unroll
  for (int j = 0; j < 8; ++j){
    const int tok = tok0 + t8*8 + j;
    if (tok >= NTOK) break;
    float* dst = seq + (size_t)tok*NF + o4*4;
    float4 s0 = *(float4*)dst;
    s0.x += acc[0][j]+bo[0]; s0.y += acc[1][j]+bo[1];
    s0.z += acc[2][j]+bo[2]; s0.w += acc[3][j]+bo[3];
    *(float4*)dst = s0;
  }
}

// ---- K5: cross block + final LN + transpose; one block per (b,t)
__global__ __launch_bounds__(256) void k_cross_final(
    const float* __restrict__ seq,
    const float* __restrict__ cbw, const float* __restrict__ cbb,
    const float* __restrict__ clnw, const float* __restrict__ clnb,
    const float* __restrict__ flnw, const float* __restrict__ flnb,
    float* __restrict__ out){
  const int b = blockIdx.x / TL, t = blockIdx.x % TL;
  __shared__ float Sm[30*NP];
  __shared__ float Cx[30*NP];
  __shared__ float mu[30], rsd[30];
  const int tid = threadIdx.x;
  for (int e = tid; e < 30*NF; e += 256){
    int k = e >> 7, n = e & 127;
    Sm[k*NP + n] = seq[((size_t)(b*30 + k)*TL + t)*NF + n];
  }
  __syncthreads();
  {
    const int n = tid & 127, kb = tid >> 7;
    const float4* wr = (const float4*)(cbw + (size_t)n*NF);
    float acc[15];
    #pragma unroll
    for (int i = 0; i < 15; ++i) acc[i] = 0.f;
    for (int k4 = 0; k4 < 32; ++k4){
      float4 w4 = wr[k4];
      #pragma unroll
      for (int i = 0; i < 15; ++i){
        float4 x4 = *((const float4*)&Sm[(kb + 2*i)*NP + k4*4]);
        acc[i] = fmaf(w4.x,x4.x, fmaf(w4.y,x4.y, fmaf(w4.z,x4.z, fmaf(w4.w,x4.w, acc[i]))));
      }
    }
    const float bb = cbb[n];
    #pragma unroll
    for (int i = 0; i < 15; ++i) Cx[(kb + 2*i)*NP + n] = acc[i] + bb;
  }
  __syncthreads();
  {
    const int w = tid >> 6, lane = tid & 63;
    for (int r = w; r < 30; r += 4){
      float2 v = *((const float2*)&Cx[r*NP + lane*2]);
      float s = v.x + v.y, s2 = v.x*v.x + v.y*v.y;
      #pragma unroll
      for (int m = 1; m < 64; m <<= 1){ s += __shfl_xor(s, m, 64); s2 += __shfl_xor(s2, m, 64); }
      if (lane == 0){
        float mm = s * (1.f/128.f);
        mu[r] = mm; rsd[r] = rsqrtf(s2*(1.f/128.f) - mm*mm + 1e-5f);
      }
    }
  }
  __syncthreads();
  for (int e = tid; e < 30*NF; e += 256){
    int k = e >> 7, n = e & 127;
    float cn = (Cx[k*NP + n] - mu[k])*rsd[k]*clnw[n] + clnb[n];
    float g = 0.5f*cn*(1.f + erff(cn*0.70710678118f));
    Cx[k*NP + n] = Sm[k*NP + n] + g;
  }
  __syncthreads();
  {
    const int w = tid >> 6, lane = tid & 63;
    for (int r = w; r < 30; r += 4){
      float2 v = *((const float2*)&Cx[r*NP + lane*2]);
      float s = v.x + v.y, s2 = v.x*v.x + v.y*v.y;
      #pragma unroll
      for (int m = 1; m < 64; m <<= 1){ s += __shfl_xor(s, m, 64); s2 += __shfl_xor(s2, m, 64); }
      if (lane == 0){
        float mm = s * (1.f/128.f);
        mu[r] = mm; rsd[r] = rsqrtf(s2*(1.f/128.f) - mm*mm + 1e-5f);
      }
    }
  }
  __syncthreads();
  for (int e = tid; e < 30*NF; e += 256){
    int n = e / 30, k = e - n*30;
    float v = (Cx[k*NP + n] - mu[k])*rsd[k]*flnw[n] + flnb[n];
    out[((size_t)(b*NF + n)*TL + t)*30 + k] = v;
  }
}

extern "C" void kernel_launch(void* const* d_in, const int* in_sizes, int n_in,
                              void* d_out, int out_size, void* d_ws, size_t ws_size,
                              hipStream_t stream){
  const float* x       = (const float*)d_in[0];
  const float* ln_w    = (const float*)d_in[1];
  const float* ln_b    = (const float*)d_in[2];
  const float* in_w    = (const float*)d_in[3];
  const float* in_b    = (const float*)d_in[4];
  const float* conv_w  = (const float*)d_in[5];
  const float* conv_b  = (const float*)d_in[6];
  const float* xp_w    = (const float*)d_in[7];
  const float* dtp_w   = (const float*)d_in[8];
  const float* dtp_b   = (const float*)d_in[9];
  const float* A_log   = (const float*)d_in[10];
  const float* Dv      = (const float*)d_in[11];
  const float* out_w   = (const float*)d_in[12];
  const float* out_b   = (const float*)d_in[13];
  const float* cb_w    = (const float*)d_in[14];
  const float* cb_b    = (const float*)d_in[15];
  const float* cb_ln_w = (const float*)d_in[16];
  const float* cb_ln_b = (const float*)d_in[17];
  const float* fin_ln_w= (const float*)d_in[18];
  const float* fin_ln_b= (const float*)d_in[19];
  float* out = (float*)d_out;

  const size_t SEQSZ = (size_t)BKS*TL*NF;
  const size_t CHSZ  = (size_t)BKS*NF*NCH*SD;
  float* ws  = (float*)d_ws;
  float* seq = ws;
  float* xcr = ws + SEQSZ;        // dead after k_conv_dt -> reused for scan scratch
  float* zb  = ws + 2*SEQSZ;
  float* xcc = ws + 3*SEQSZ;
  float* dtb = ws + 4*SEQSZ;
  float* yb  = ws + 5*SEQSZ;
  float* Bmb = ws + 6*SEQSZ;
  float* Cmb = Bmb + (size_t)BKS*TL*SD;
  float* ap    = xcr;
  float* hfb   = xcr + CHSZ;
  float* hinit = xcr + 2*CHSZ;
  if (ws_size < (6*SEQSZ + 2*(size_t)BKS*TL*SD)*sizeof(float)) return;

  k_ingest<<<2*TL, 256, 0, stream>>>(x, seq);
  for (int l = 0; l < 4; ++l){
    k_ln_inproj<<<NBLK, 256, 0, stream>>>(seq, ln_w + l*NF, ln_b + l*NF,
        in_w + (size_t)l*2*NF*NF, in_b + l*2*NF, xcr, zb);
    k_conv_dt<<<BKS*NCH, 256, 0, stream>>>(xcr, conv_w + (size_t)l*NF*4, conv_b + l*NF,
        xp_w + (size_t)l*32*NF, dtp_w + (size_t)l*NF*RD, dtp_b + l*NF, xcc, dtb, Bmb, Cmb);
    k_scan_pass1<<<BKS*NCH, NF, 0, stream>>>(dtb, xcc, Bmb, A_log + (size_t)l*NF*SD, ap, hfb);
    k_scan_combine<<<BKS, NF, 0, stream>>>(ap, hfb, hinit);
    k_scan_pass2<<<BKS*NCH, NF, 0, stream>>>(dtb, xcc, Bmb, Cmb, A_log + (size_t)l*NF*SD, hinit, yb);
    k_gate_out<<<NBLK, 256, 0, stream>>>(yb, xcc, zb, Dv + l*NF,
        out_w + (size_t)l*NF*NF, out_b + l*NF, seq);
  }
  k_cross_final<<<2*TL, 256, 0, stream>>>(seq, cb_w, cb_b, cb_ln_w, cb_ln_b, fin_ln_w, fin_ln_b, out);
}

// Round 5
// 1085.272 us; speedup vs baseline: 1.3829x; 1.0504x over previous
//
#include <hip/hip_runtime.h>
#include <math.h>

#define BKS 60      // B*K sequences
#define TL  1000    // T
#define NF  128     // N features
#define SD  12      // state dim S
#define RD  8       // dt rank
#define NCH 25      // scan chunks
#define CLEN 40     // chunk length (NCH*CLEN == TL)
#define NTOK (BKS*TL)
#define MT  64      // GEMM token tile (ln_inproj / gate_out)
#define NBLK ((NTOK + MT - 1)/MT)   // 938
#define XSP 68      // xs transposed stride
#define WSP 260     // in_proj w_lds stride (256+4)
#define GWS 132     // 128-out w_lds stride (128+4)
#define CT  32      // cross_final token tile
#define CXS 36      // cross_final xs stride (32+4)

__device__ __forceinline__ float siluf(float x){ return x / (1.f + __expf(-x)); }
__device__ __forceinline__ float softplusf(float x){
  if (x > 20.f) return x;
  float e = __expf(x);
  return (x < -20.f) ? e : __logf(1.f + e);
}

// ---- K0: x (B,N,T,K) -> seq (B*K, T, N), one block per (b,t)
__global__ __launch_bounds__(256) void k_ingest(const float* __restrict__ x, float* __restrict__ seq){
  const int b = blockIdx.x / TL, t = blockIdx.x % TL;
  __shared__ float tile[30*NF];
  for (int e = threadIdx.x; e < 30*NF; e += 256){
    int n = e / 30, k = e - n*30;
    tile[k*NF + n] = x[((size_t)(b*NF + n)*TL + t)*30 + k];
  }
  __syncthreads();
  const size_t base = ((size_t)b*30)*TL*NF + (size_t)t*NF;
  for (int e = threadIdx.x; e < 30*NF; e += 256){
    int k = e >> 7, n = e & 127;
    seq[base + (size_t)k*TL*NF + n] = tile[e];
  }
}

// ---- K1: LayerNorm + in_proj. 64 tokens/block, weights staged in LDS (k-tiled).
__global__ __launch_bounds__(256) void k_ln_inproj(
    const float* __restrict__ seq, const float* __restrict__ lnw, const float* __restrict__ lnb,
    const float* __restrict__ iw, const float* __restrict__ ib,
    float* __restrict__ xcr, float* __restrict__ zb){
  __shared__ float xs[NF*XSP];    // [k][t]
  __shared__ float wl[16*WSP];    // [kl][o]
  const int tid = threadIdx.x;
  const int tok0 = blockIdx.x * MT;

  {
    const int j = tid >> 4, l16 = tid & 15;
    for (int it = 0; it < 4; ++it){
      const int t = j + 16*it;
      const int tok = tok0 + t;
      float v[8]; float s = 0.f, s2 = 0.f;
      if (tok < NTOK){
        const float* sp = seq + (size_t)tok*NF;
        #pragma unroll
        for (int i = 0; i < 8; ++i){ float f = sp[l16 + 16*i]; v[i] = f; s += f; s2 += f*f; }
      } else {
        #pragma unroll
        for (int i = 0; i < 8; ++i) v[i] = 0.f;
      }
      #pragma unroll
      for (int m = 1; m < 16; m <<= 1){ s += __shfl_xor(s, m, 64); s2 += __shfl_xor(s2, m, 64); }
      const float mean = s * (1.f/128.f);
      const float rstd = rsqrtf(s2*(1.f/128.f) - mean*mean + 1e-5f);
      #pragma unroll
      for (int i = 0; i < 8; ++i){
        int n = l16 + 16*i;
        xs[n*XSP + t] = (v[i]-mean)*rstd*lnw[n] + lnb[n];
      }
    }
  }

  const int o8 = tid & 31, t8 = tid >> 5;
  float acc[8][8];
  #pragma unroll
  for (int o = 0; o < 8; ++o)
    #pragma unroll
    for (int t = 0; t < 8; ++t) acc[o][t] = 0.f;

  for (int kt = 0; kt < 8; ++kt){
    __syncthreads();
    {
      const int ch = tid & 3, row = tid >> 2;
      #pragma unroll
      for (int p = 0; p < 4; ++p){
        const int o = row + 64*p;
        const float4 w4 = *(const float4*)(iw + (size_t)o*NF + kt*16 + ch*4);
        const int kl = ch*4;
        wl[(kl+0)*WSP + o] = w4.x;
        wl[(kl+1)*WSP + o] = w4.y;
        wl[(kl+2)*WSP + o] = w4.z;
        wl[(kl+3)*WSP + o] = w4.w;
      }
    }
    __syncthreads();
    for (int kl = 0; kl < 16; ++kl){
      const int kg = kt*16 + kl;
      const float4 wa = *(const float4*)&wl[kl*WSP + o8*8];
      const float4 wb = *(const float4*)&wl[kl*WSP + o8*8 + 4];
      const float4 xa = *(const float4*)&xs[kg*XSP + t8*8];
      const float4 xb = *(const float4*)&xs[kg*XSP + t8*8 + 4];
      const float wv[8] = {wa.x,wa.y,wa.z,wa.w, wb.x,wb.y,wb.z,wb.w};
      const float xv[8] = {xa.x,xa.y,xa.z,xa.w, xb.x,xb.y,xb.z,xb.w};
      #pragma unroll
      for (int o = 0; o < 8; ++o)
        #pragma unroll
        for (int t = 0; t < 8; ++t)
          acc[o][t] = fmaf(wv[o], xv[t], acc[o][t]);
    }
  }

  float bo[8];
  #pragma unroll
  for (int i = 0; i < 8; ++i) bo[i] = ib[o8*8 + i];
  #pragma unroll
  for (int j = 0; j < 8; ++j){
    const int tok = tok0 + t8*8 + j;
    if (tok >= NTOK) break;
    float4 r0, r1;
    r0.x = acc[0][j]+bo[0]; r0.y = acc[1][j]+bo[1]; r0.z = acc[2][j]+bo[2]; r0.w = acc[3][j]+bo[3];
    r1.x = acc[4][j]+bo[4]; r1.y = acc[5][j]+bo[5]; r1.z = acc[6][j]+bo[6]; r1.w = acc[7][j]+bo[7];
    if (o8 < 16){
      float* dst = xcr + (size_t)tok*NF + o8*8;
      *(float4*)dst = r0; *(float4*)(dst+4) = r1;
    } else {
      float* dst = zb + (size_t)tok*NF + (o8*8 - 128);
      *(float4*)dst = r0; *(float4*)(dst+4) = r1;
    }
  }
}

// ---- K2 (unfused fallback): conv+silu -> x-proj -> dt/B/C, 40 tokens/block
__global__ __launch_bounds__(256) void k_conv_dt(
    const float* __restrict__ xcr,
    const float* __restrict__ cw, const float* __restrict__ cb,
    const float* __restrict__ xw, const float* __restrict__ dw, const float* __restrict__ db,
    float* __restrict__ xcc, float* __restrict__ dtb,
    float* __restrict__ Bmb, float* __restrict__ Cmb){
  __shared__ float sxr[(CLEN+3)*NF];
  __shared__ float sxc[CLEN*NF];
  __shared__ float sdbc[CLEN*32];
  const int sq = blockIdx.x / NCH, cblk = blockIdx.x - sq*NCH;
  const int t0 = cblk*CLEN;
  const int tid = threadIdx.x;

  for (int e = tid; e < (CLEN+3)*NF; e += 256){
    int r = e >> 7, n = e & 127;
    int t = t0 - 3 + r;
    sxr[e] = (t >= 0) ? xcr[((size_t)sq*TL + t)*NF + n] : 0.f;
  }
  __syncthreads();

  #pragma unroll
  for (int i = 0; i < (CLEN*NF)/256; ++i){
    int e = tid + i*256;
    int r = e >> 7, n = e & 127;
    float a = cb[n];
    #pragma unroll
    for (int k = 0; k < 4; ++k)
      a = fmaf(sxr[(r+k)*NF + n], cw[n*4 + k], a);
    float v = siluf(a);
    sxc[e] = v;
    xcc[((size_t)sq*TL + t0)*NF + e] = v;
  }
  __syncthreads();

  {
    const int o = tid & 31, jg = tid >> 5;
    const float4* wr = (const float4*)(xw + (size_t)o*NF);
    float acc[5];
    #pragma unroll
    for (int j = 0; j < 5; ++j) acc[j] = 0.f;
    for (int k4 = 0; k4 < 32; ++k4){
      float4 w4 = wr[k4];
      #pragma unroll
      for (int j = 0; j < 5; ++j){
        float4 x4 = *((const float4*)&sxc[(jg*5 + j)*NF + k4*4]);
        acc[j] = fmaf(w4.x,x4.x, fmaf(w4.y,x4.y, fmaf(w4.z,x4.z, fmaf(w4.w,x4.w, acc[j]))));
      }
    }
    #pragma unroll
    for (int j = 0; j < 5; ++j) sdbc[(jg*5 + j)*32 + o] = acc[j];
  }
  __syncthreads();

  #pragma unroll
  for (int i = 0; i < (CLEN*NF)/256; ++i){
    int e = tid + i*256;
    int r = e >> 7, n = e & 127;
    float acc = db[n];
    #pragma unroll
    for (int q = 0; q < 8; ++q)
      acc = fmaf(sdbc[r*32 + q], dw[n*8 + q], acc);
    dtb[((size_t)sq*TL + t0)*NF + e] = softplusf(acc);
  }
  for (int e = tid; e < CLEN*2*SD; e += 256){
    int r = e / (2*SD), c = e - r*2*SD;
    float v = sdbc[r*32 + 8 + c];
    size_t tok = (size_t)sq*TL + t0 + r;
    if (c < SD) Bmb[tok*SD + c] = v;
    else        Cmb[tok*SD + (c - SD)] = v;
  }
}

// ---- K2f (fused): conv+silu -> x-proj -> dt/B/C -> scan pass 1, all in LDS.
// 256 threads: scan phase splits 12 states across 2 thread-groups.
__global__ __launch_bounds__(256) void k_conv_scan1(
    const float* __restrict__ xcr,
    const float* __restrict__ cw, const float* __restrict__ cb,
    const float* __restrict__ xw, const float* __restrict__ dw, const float* __restrict__ db,
    const float* __restrict__ alog,
    float* __restrict__ xcc, float* __restrict__ dtb,
    float* __restrict__ Bmb, float* __restrict__ Cmb,
    float* __restrict__ ap, float* __restrict__ hfb){
  __shared__ float smem[(CLEN+3)*NF + CLEN*NF + CLEN*32];
  float* sxr  = smem;                      // (CLEN+3)*NF, dead after conv phase
  float* sdt  = smem;                      // aliases sxr (used after 2 barriers)
  float* sxc  = smem + (CLEN+3)*NF;
  float* sdbc = sxc + CLEN*NF;
  const int bid = blockIdx.x;
  const int sq = bid / NCH, cblk = bid - sq*NCH;
  const int t0 = cblk*CLEN;
  const int tid = threadIdx.x;

  for (int e = tid; e < (CLEN+3)*NF; e += 256){
    int r = e >> 7, n = e & 127;
    int t = t0 - 3 + r;
    sxr[e] = (t >= 0) ? xcr[((size_t)sq*TL + t)*NF + n] : 0.f;
  }
  __syncthreads();

  // conv + silu -> sxc + global xcc (sxr still live here)
  float convv[(CLEN*NF)/256];
  #pragma unroll
  for (int i = 0; i < (CLEN*NF)/256; ++i){
    int e = tid + i*256;
    int r = e >> 7, n = e & 127;
    float a = cb[n];
    #pragma unroll
    for (int k = 0; k < 4; ++k)
      a = fmaf(sxr[(r+k)*NF + n], cw[n*4 + k], a);
    convv[i] = siluf(a);
  }
  __syncthreads();   // sxr reads done; safe to write sxc (and later sdt alias)
  #pragma unroll
  for (int i = 0; i < (CLEN*NF)/256; ++i){
    int e = tid + i*256;
    sxc[e] = convv[i];
    xcc[((size_t)sq*TL + t0)*NF + e] = convv[i];
  }
  __syncthreads();

  // x-proj
  {
    const int o = tid & 31, jg = tid >> 5;
    const float4* wr = (const float4*)(xw + (size_t)o*NF);
    float acc[5];
    #pragma unroll
    for (int j = 0; j < 5; ++j) acc[j] = 0.f;
    for (int k4 = 0; k4 < 32; ++k4){
      float4 w4 = wr[k4];
      #pragma unroll
      for (int j = 0; j < 5; ++j){
        float4 x4 = *((const float4*)&sxc[(jg*5 + j)*NF + k4*4]);
        acc[j] = fmaf(w4.x,x4.x, fmaf(w4.y,x4.y, fmaf(w4.z,x4.z, fmaf(w4.w,x4.w, acc[j]))));
      }
    }
    #pragma unroll
    for (int j = 0; j < 5; ++j) sdbc[(jg*5 + j)*32 + o] = acc[j];
  }
  __syncthreads();

  // dt projection -> sdt (alias of sxr; safe: 2 barriers since last sxr read) + global
  #pragma unroll
  for (int i = 0; i < (CLEN*NF)/256; ++i){
    int e = tid + i*256;
    int r = e >> 7, n = e & 127;
    float acc = db[n];
    #pragma unroll
    for (int q = 0; q < 8; ++q)
      acc = fmaf(sdbc[r*32 + q], dw[n*8 + q], acc);
    float dtv = softplusf(acc);
    sdt[e] = dtv;
    dtb[((size_t)sq*TL + t0)*NF + e] = dtv;
  }
  for (int e = tid; e < CLEN*2*SD; e += 256){
    int r = e / (2*SD), c = e - r*2*SD;
    float v = sdbc[r*32 + 8 + c];
    size_t tok = (size_t)sq*TL + t0 + r;
    if (c < SD) Bmb[tok*SD + c] = v;
    else        Cmb[tok*SD + (c - SD)] = v;
  }
  __syncthreads();

  // scan pass 1: thread (n, p) handles states p*6..p*6+5
  {
    const int n = tid & 127, p = tid >> 7;
    float Av[6], h[6], apv[6];
    #pragma unroll
    for (int s = 0; s < 6; ++s){
      Av[s] = -__expf(alog[(size_t)n*SD + p*6 + s]);
      h[s] = 0.f; apv[s] = 1.f;
    }
    for (int tt = 0; tt < CLEN; ++tt){
      float dtv = sdt[tt*NF + n];
      float dx  = dtv * sxc[tt*NF + n];
      #pragma unroll
      for (int s = 0; s < 6; ++s){
        float Bv = sdbc[tt*32 + 8 + p*6 + s];
        float dA = __expf(dtv*Av[s]);
        h[s] = fmaf(dA, h[s], dx*Bv);
        apv[s] *= dA;
      }
    }
    const size_t base = (size_t)bid*SD*NF + n;
    #pragma unroll
    for (int s = 0; s < 6; ++s){
      ap [base + (p*6+s)*NF] = apv[s];
      hfb[base + (p*6+s)*NF] = h[s];
    }
  }
}

// ---- K3a (unfused fallback): scan pass 1
__global__ __launch_bounds__(128) void k_scan_pass1(
    const float* __restrict__ dtb, const float* __restrict__ xcc,
    const float* __restrict__ Bmb, const float* __restrict__ alog,
    float* __restrict__ ap, float* __restrict__ hfb){
  const int bid = blockIdx.x;
  const int sq = bid / NCH, c = bid - sq*NCH;
  const int n = threadIdx.x;
  const float4* A4 = (const float4*)(alog + (size_t)n*SD);
  float4 Aa = A4[0], Ab = A4[1], Ac = A4[2];
  float Av[SD] = {Aa.x,Aa.y,Aa.z,Aa.w, Ab.x,Ab.y,Ab.z,Ab.w, Ac.x,Ac.y,Ac.z,Ac.w};
  #pragma unroll
  for (int s = 0; s < SD; ++s) Av[s] = -__expf(Av[s]);
  float h[SD], apv[SD];
  #pragma unroll
  for (int s = 0; s < SD; ++s){ h[s] = 0.f; apv[s] = 1.f; }
  const size_t tok0 = (size_t)sq*TL + c*CLEN;
  for (int tt = 0; tt < CLEN; ++tt){
    const size_t tok = tok0 + tt;
    float dtv = dtb[tok*NF + n];
    float dx  = dtv * xcc[tok*NF + n];
    const float4* B4 = (const float4*)(Bmb + tok*SD);
    float4 Ba = B4[0], Bb = B4[1], Bc = B4[2];
    float Bv[SD] = {Ba.x,Ba.y,Ba.z,Ba.w, Bb.x,Bb.y,Bb.z,Bb.w, Bc.x,Bc.y,Bc.z,Bc.w};
    #pragma unroll
    for (int s = 0; s < SD; ++s){
      float dA = __expf(dtv*Av[s]);
      h[s] = fmaf(dA, h[s], dx*Bv[s]);
      apv[s] *= dA;
    }
  }
  const size_t base = (size_t)bid*SD*NF + n;
  #pragma unroll
  for (int s = 0; s < SD; ++s){ ap[base + s*NF] = apv[s]; hfb[base + s*NF] = h[s]; }
}

// ---- K3b: sequential combine across chunks
__global__ __launch_bounds__(128) void k_scan_combine(
    const float* __restrict__ ap, const float* __restrict__ hfb, float* __restrict__ hinit){
  const int sq = blockIdx.x;
  const int n = threadIdx.x;
  float h[SD];
  #pragma unroll
  for (int s = 0; s < SD; ++s) h[s] = 0.f;
  for (int c = 0; c < NCH; ++c){
    const size_t base = ((size_t)sq*NCH + c)*SD*NF + n;
    #pragma unroll
    for (int s = 0; s < SD; ++s){
      hinit[base + s*NF] = h[s];
      h[s] = fmaf(ap[base + s*NF], h[s], hfb[base + s*NF]);
    }
  }
}

// ---- K3c: scan pass 2 + gate: yb = (y + Dv*xc)*silu(z)
__global__ __launch_bounds__(128) void k_scan_pass2(
    const float* __restrict__ dtb, const float* __restrict__ xcc,
    const float* __restrict__ Bmb, const float* __restrict__ Cmb,
    const float* __restrict__ alog, const float* __restrict__ hinit,
    const float* __restrict__ zb, const float* __restrict__ Dv,
    float* __restrict__ yb){
  const int bid = blockIdx.x;
  const int sq = bid / NCH, c = bid - sq*NCH;
  const int n = threadIdx.x;
  const float4* A4 = (const float4*)(alog + (size_t)n*SD);
  float4 Aa = A4[0], Ab = A4[1], Ac = A4[2];
  float Av[SD] = {Aa.x,Aa.y,Aa.z,Aa.w, Ab.x,Ab.y,Ab.z,Ab.w, Ac.x,Ac.y,Ac.z,Ac.w};
  #pragma unroll
  for (int s = 0; s < SD; ++s) Av[s] = -__expf(Av[s]);
  const float dvn = Dv[n];
  float h[SD];
  const size_t hbase = (size_t)bid*SD*NF + n;
  #pragma unroll
  for (int s = 0; s < SD; ++s) h[s] = hinit[hbase + s*NF];
  const size_t tok0 = (size_t)sq*TL + c*CLEN;
  for (int tt = 0; tt < CLEN; ++tt){
    const size_t tok = tok0 + tt;
    float dtv = dtb[tok*NF + n];
    float xcv = xcc[tok*NF + n];
    float dx  = dtv * xcv;
    const float4* B4 = (const float4*)(Bmb + tok*SD);
    const float4* C4 = (const float4*)(Cmb + tok*SD);
    float4 Ba=B4[0], Bb=B4[1], Bc=B4[2];
    float4 Ca=C4[0], Cb=C4[1], Cc=C4[2];
    float Bv[SD] = {Ba.x,Ba.y,Ba.z,Ba.w, Bb.x,Bb.y,Bb.z,Bb.w, Bc.x,Bc.y,Bc.z,Bc.w};
    float Cv[SD] = {Ca.x,Ca.y,Ca.z,Ca.w, Cb.x,Cb.y,Cb.z,Cb.w, Cc.x,Cc.y,Cc.z,Cc.w};
    float yv = 0.f;
    #pragma unroll
    for (int s = 0; s < SD; ++s){
      float dA = __expf(dtv*Av[s]);
      h[s] = fmaf(dA, h[s], dx*Bv[s]);
      yv = fmaf(h[s], Cv[s], yv);
    }
    float zv = zb[tok*NF + n];
    yb[tok*NF + n] = fmaf(dvn, xcv, yv) * siluf(zv);
  }
}

// ---- K4: seq += yb @ ow^T + ob. 64 tokens/block, tiled GEMM (yb already gated).
__global__ __launch_bounds__(256) void k_gate_out(
    const float* __restrict__ yb,
    const float* __restrict__ ow, const float* __restrict__ ob,
    float* __restrict__ seq){
  __shared__ float xs[NF*XSP];    // [n][t]
  __shared__ float wl[32*GWS];    // [kl][o]
  const int tid = threadIdx.x;
  const int tok0 = blockIdx.x * MT;

  #pragma unroll
  for (int i = 0; i < 32; ++i){
    const int e = tid + i*256;
    const int r = e >> 7, n = e & 127;
    const int tok = tok0 + r;
    xs[n*XSP + r] = (tok < NTOK) ? yb[(size_t)tok*NF + n] : 0.f;
  }

  const int o4 = tid & 31, t8 = tid >> 5;
  float acc[4][8];
  #pragma unroll
  for (int o = 0; o < 4; ++o)
    #pragma unroll
    for (int t = 0; t < 8; ++t) acc[o][t] = 0.f;

  for (int kt = 0; kt < 4; ++kt){
    __syncthreads();
    {
      const int ch = tid & 7, row = tid >> 3;
      #pragma unroll
      for (int p = 0; p < 4; ++p){
        const int o = row + 32*p;
        const float4 w4 = *(const float4*)(ow + (size_t)o*NF + kt*32 + ch*4);
        const int kl = ch*4;
        wl[(kl+0)*GWS + o] = w4.x;
        wl[(kl+1)*GWS + o] = w4.y;
        wl[(kl+2)*GWS + o] = w4.z;
        wl[(kl+3)*GWS + o] = w4.w;
      }
    }
    __syncthreads();
    for (int kl = 0; kl < 32; ++kl){
      const int kg = kt*32 + kl;
      const float4 wa = *(const float4*)&wl[kl*GWS + o4*4];
      const float4 xa = *(const float4*)&xs[kg*XSP + t8*8];
      const float4 xb = *(const float4*)&xs[kg*XSP + t8*8 + 4];
      const float wv[4] = {wa.x,wa.y,wa.z,wa.w};
      const float xv[8] = {xa.x,xa.y,xa.z,xa.w, xb.x,xb.y,xb.z,xb.w};
      #pragma unroll
      for (int o = 0; o < 4; ++o)
        #pragma unroll
        for (int t = 0; t < 8; ++t)
          acc[o][t] = fmaf(wv[o], xv[t], acc[o][t]);
    }
  }

  float bo[4];
  #pragma unroll
  for (int i = 0; i < 4; ++i) bo[i] = ob[o4*4 + i];
  #pragma unroll
  for (int j = 0; j < 8; ++j){
    const int tok = tok0 + t8*8 + j;
    if (tok >= NTOK) break;
    float* dst = seq + (size_t)tok*NF + o4*4;
    float4 s0 = *(float4*)dst;
    s0.x += acc[0][j]+bo[0]; s0.y += acc[1][j]+bo[1];
    s0.z += acc[2][j]+bo[2]; s0.w += acc[3][j]+bo[3];
    *(float4*)dst = s0;
  }
}

// ---- K5: cross block + final LN + transpose. 32 tokens/block, staged-LDS GEMM.
__global__ __launch_bounds__(256) void k_cross_final(
    const float* __restrict__ seq,
    const float* __restrict__ cbw, const float* __restrict__ cbb,
    const float* __restrict__ clnw, const float* __restrict__ clnb,
    const float* __restrict__ flnw, const float* __restrict__ flnb,
    float* __restrict__ out){
  __shared__ float xs[NF*CXS];     // main transposed [n][t]
  __shared__ float wl[32*GWS];     // [kl][o]
  __shared__ float Cx[CT*GWS];     // [t][o]
  __shared__ float mu[CT], rsd[CT];
  const int tid = threadIdx.x;
  const int tok0 = blockIdx.x * CT;   // 1875 blocks exact

  // load main transposed (coalesced global read per wave)
  #pragma unroll
  for (int i = 0; i < 16; ++i){
    int e = tid + i*256;
    int r = e >> 7, n = e & 127;
    int tok = tok0 + r;
    int b = tok / 30000, rr = tok - b*30000;
    int t = rr / 30, k = rr - t*30;
    xs[n*CXS + r] = seq[((size_t)(b*30 + k)*TL + t)*NF + n];
  }

  const int o4 = tid & 31, t4 = tid >> 5;
  float acc[4][4];
  #pragma unroll
  for (int o = 0; o < 4; ++o)
    #pragma unroll
    for (int t = 0; t < 4; ++t) acc[o][t] = 0.f;

  for (int kt = 0; kt < 4; ++kt){
    __syncthreads();
    {
      const int ch = tid & 7, row = tid >> 3;
      #pragma unroll
      for (int p = 0; p < 4; ++p){
        const int o = row + 32*p;
        const float4 w4 = *(const float4*)(cbw + (size_t)o*NF + kt*32 + ch*4);
        const int kl = ch*4;
        wl[(kl+0)*GWS + o] = w4.x;
        wl[(kl+1)*GWS + o] = w4.y;
        wl[(kl+2)*GWS + o] = w4.z;
        wl[(kl+3)*GWS + o] = w4.w;
      }
    }
    __syncthreads();
    for (int kl = 0; kl < 32; ++kl){
      const int kg = kt*32 + kl;
      const float4 wa = *(const float4*)&wl[kl*GWS + o4*4];
      const float4 xa = *(const float4*)&xs[kg*CXS + t4*4];
      const float wv[4] = {wa.x,wa.y,wa.z,wa.w};
      const float xv[4] = {xa.x,xa.y,xa.z,xa.w};
      #pragma unroll
      for (int o = 0; o < 4; ++o)
        #pragma unroll
        for (int t = 0; t < 4; ++t)
          acc[o][t] = fmaf(wv[o], xv[t], acc[o][t]);
    }
  }

  // write Cx[t][o] += cb_b
  {
    const float4 bb = *(const float4*)(cbb + o4*4);
    #pragma unroll
    for (int j = 0; j < 4; ++j){
      float4 v;
      v.x = acc[0][j]+bb.x; v.y = acc[1][j]+bb.y; v.z = acc[2][j]+bb.z; v.w = acc[3][j]+bb.w;
      *(float4*)&Cx[(t4*4+j)*GWS + o4*4] = v;
    }
  }
  __syncthreads();

  // LN1 over Cx rows (wave-parallel)
  {
    const int w = tid >> 6, lane = tid & 63;
    for (int r = w; r < CT; r += 4){
      float a = Cx[r*GWS + lane], b2 = Cx[r*GWS + lane + 64];
      float s = a + b2, s2 = a*a + b2*b2;
      #pragma unroll
      for (int m = 1; m < 64; m <<= 1){ s += __shfl_xor(s, m, 64); s2 += __shfl_xor(s2, m, 64); }
      if (lane == 0){
        float mm = s * (1.f/128.f);
        mu[r] = mm; rsd[r] = rsqrtf(s2*(1.f/128.f) - mm*mm + 1e-5f);
      }
    }
  }
  __syncthreads();
  // gelu + residual
  #pragma unroll
  for (int i = 0; i < 16; ++i){
    int e = tid + i*256;
    int r = e >> 7, n = e & 127;
    float cn = (Cx[r*GWS + n] - mu[r])*rsd[r]*clnw[n] + clnb[n];
    float g = 0.5f*cn*(1.f + erff(cn*0.70710678118f));
    Cx[r*GWS + n] = xs[n*CXS + r] + g;
  }
  __syncthreads();
  // LN2
  {
    const int w = tid >> 6, lane = tid & 63;
    for (int r = w; r < CT; r += 4){
      float a = Cx[r*GWS + lane], b2 = Cx[r*GWS + lane + 64];
      float s = a + b2, s2 = a*a + b2*b2;
      #pragma unroll
      for (int m = 1; m < 64; m <<= 1){ s += __shfl_xor(s, m, 64); s2 += __shfl_xor(s2, m, 64); }
      if (lane == 0){
        float mm = s * (1.f/128.f);
        mu[r] = mm; rsd[r] = rsqrtf(s2*(1.f/128.f) - mm*mm + 1e-5f);
      }
    }
  }
  __syncthreads();
  // final write, n-major for coalescing
  #pragma unroll
  for (int i = 0; i < 16; ++i){
    int e = tid + i*256;
    int n = e >> 5, j = e & 31;
    int tok = tok0 + j;
    int b = tok / 30000, rr = tok - b*30000;
    float v = (Cx[j*GWS + n] - mu[j])*rsd[j]*flnw[n] + flnb[n];
    out[(size_t)(b*NF + n)*30000 + rr] = v;
  }
}

extern "C" void kernel_launch(void* const* d_in, const int* in_sizes, int n_in,
                              void* d_out, int out_size, void* d_ws, size_t ws_size,
                              hipStream_t stream){
  const float* x       = (const float*)d_in[0];
  const float* ln_w    = (const float*)d_in[1];
  const float* ln_b    = (const float*)d_in[2];
  const float* in_w    = (const float*)d_in[3];
  const float* in_b    = (const float*)d_in[4];
  const float* conv_w  = (const float*)d_in[5];
  const float* conv_b  = (const float*)d_in[6];
  const float* xp_w    = (const float*)d_in[7];
  const float* dtp_w   = (const float*)d_in[8];
  const float* dtp_b   = (const float*)d_in[9];
  const float* A_log   = (const float*)d_in[10];
  const float* Dv      = (const float*)d_in[11];
  const float* out_w   = (const float*)d_in[12];
  const float* out_b   = (const float*)d_in[13];
  const float* cb_w    = (const float*)d_in[14];
  const float* cb_b    = (const float*)d_in[15];
  const float* cb_ln_w = (const float*)d_in[16];
  const float* cb_ln_b = (const float*)d_in[17];
  const float* fin_ln_w= (const float*)d_in[18];
  const float* fin_ln_b= (const float*)d_in[19];
  float* out = (float*)d_out;

  const size_t SEQSZ = (size_t)BKS*TL*NF;        // 7,680,000
  const size_t CHSZ  = (size_t)BKS*NF*NCH*SD;    // 2,304,000
  const size_t BASE  = 6*SEQSZ + 2*(size_t)BKS*TL*SD;  // 47,520,000 floats
  float* ws  = (float*)d_ws;
  float* seq = ws;
  float* xcr = ws + SEQSZ;
  float* zb  = ws + 2*SEQSZ;
  float* xcc = ws + 3*SEQSZ;
  float* dtb = ws + 4*SEQSZ;
  float* yb  = ws + 5*SEQSZ;
  float* Bmb = ws + 6*SEQSZ;
  float* Cmb = Bmb + (size_t)BKS*TL*SD;
  if (ws_size < BASE*sizeof(float)) return;

  // fused conv+scan1 path needs non-aliased scan scratch
  const bool fused = ws_size >= (BASE + 3*CHSZ)*sizeof(float);
  float *ap, *hfb, *hinit;
  if (fused){
    ap    = ws + BASE;
    hfb   = ws + BASE + CHSZ;
    hinit = ws + BASE + 2*CHSZ;
  } else {
    ap    = xcr;            // aliases xcr (safe: pass1 runs after conv_dt completes)
    hfb   = xcr + CHSZ;
    hinit = xcr + 2*CHSZ;
  }

  k_ingest<<<2*TL, 256, 0, stream>>>(x, seq);
  for (int l = 0; l < 4; ++l){
    k_ln_inproj<<<NBLK, 256, 0, stream>>>(seq, ln_w + l*NF, ln_b + l*NF,
        in_w + (size_t)l*2*NF*NF, in_b + l*2*NF, xcr, zb);
    if (fused){
      k_conv_scan1<<<BKS*NCH, 256, 0, stream>>>(xcr, conv_w + (size_t)l*NF*4, conv_b + l*NF,
          xp_w + (size_t)l*32*NF, dtp_w + (size_t)l*NF*RD, dtp_b + l*NF,
          A_log + (size_t)l*NF*SD, xcc, dtb, Bmb, Cmb, ap, hfb);
    } else {
      k_conv_dt<<<BKS*NCH, 256, 0, stream>>>(xcr, conv_w + (size_t)l*NF*4, conv_b + l*NF,
          xp_w + (size_t)l*32*NF, dtp_w + (size_t)l*NF*RD, dtp_b + l*NF, xcc, dtb, Bmb, Cmb);
      k_scan_pass1<<<BKS*NCH, NF, 0, stream>>>(dtb, xcc, Bmb, A_log + (size_t)l*NF*SD, ap, hfb);
    }
    k_scan_combine<<<BKS, NF, 0, stream>>>(ap, hfb, hinit);
    k_scan_pass2<<<BKS*NCH, NF, 0, stream>>>(dtb, xcc, Bmb, Cmb, A_log + (size_t)l*NF*SD,
        hinit, zb, Dv + l*NF, yb);
    k_gate_out<<<NBLK, 256, 0, stream>>>(yb, out_w + (size_t)l*NF*NF, out_b + l*NF, seq);
  }
  k_cross_final<<<NTOK/CT, 256, 0, stream>>>(seq, cb_w, cb_b, cb_ln_w, cb_ln_b, fin_ln_w, fin_ln_b, out);
}